// Round 5
// baseline (98.911 us; speedup 1.0000x reference)
//
#include <hip/hip_runtime.h>

#define D 256
#define MAXB 128

typedef float f32x4 __attribute__((ext_vector_type(4)));

// Source-major fused kernel:
//  - every block computes the 4 offset scans (128 lengths, L2-hit loads, cheap)
//  - block 0 writes the out_len tail (as float values)
//  - ctx loop: few waves copy the (tiny) contextual rows via jagged binsearch
//  - main loop: one wave per source TOKEN per iteration -> one binsearch gives
//    TWO 1KB rows (item + action), contiguous 2KB store, 2 loads in flight.
__global__ __launch_bounds__(256) void hstu_preproc_fused(
    const float* __restrict__ item, const float* __restrict__ action,
    const float* __restrict__ c0v, const float* __restrict__ c1v,
    const int* __restrict__ item_len, const int* __restrict__ c0_len,
    const int* __restrict__ c1_len,
    float* __restrict__ out, int total_rows, int total_tok, int Bn) {
    __shared__ int s_oo[MAXB + 1];
    __shared__ int s_io[MAXB + 1];
    __shared__ int s_c0[MAXB + 1];
    __shared__ int s_c1[MAXB + 1];

    int t = threadIdx.x;
    int li = 0, l0 = 0, l1 = 0;
    if (t < Bn) {
        li = item_len[t];
        l0 = c0_len[t];
        l1 = c1_len[t];
    }
    if (t == 0) { s_oo[0] = 0; s_io[0] = 0; s_c0[0] = 0; s_c1[0] = 0; }
    if (t < Bn) {
        s_oo[t + 1] = 2 * li + l0 + l1;
        s_io[t + 1] = li;
        s_c0[t + 1] = l0;
        s_c1[t + 1] = l1;
    }
    __syncthreads();
    // Hillis-Steele inclusive scan over positions 1..Bn -> exclusive offsets [0..Bn]
    for (int off = 1; off < Bn; off <<= 1) {
        int a = 0, b = 0, c = 0, d = 0;
        int idx = t + 1;
        bool act = (t < Bn) && (idx > off);
        if (act) {
            a = s_oo[idx - off];
            b = s_io[idx - off];
            c = s_c0[idx - off];
            d = s_c1[idx - off];
        }
        __syncthreads();
        if (act) {
            s_oo[idx] += a;
            s_io[idx] += b;
            s_c0[idx] += c;
            s_c1[idx] += d;
        }
        __syncthreads();
    }

    // out_len tail (second reference output), float-encoded, block 0 only
    if (blockIdx.x == 0 && t < Bn) {
        out[(size_t)total_rows * D + t] = (float)(s_oo[t + 1] - s_oo[t]);
    }

    int wave = t >> 6;
    int lane = t & 63;
    int gwave = blockIdx.x * 4 + wave;
    int nwaves = gridDim.x * 4;

    // ---- ctx rows (small: sum(l0)+sum(l1) rows, 0.1% of traffic) ----
    int totc = s_c0[Bn] + s_c1[Bn];
    for (int c = gwave; c < totc; c += nwaves) {
        int lo = 0, hi = Bn;
        while (hi - lo > 1) {
            int mid = (lo + hi) >> 1;
            if (c >= s_c0[mid] + s_c1[mid]) lo = mid; else hi = mid;
        }
        int s = lo;
        int pos = c - (s_c0[s] + s_c1[s]);
        int l0c = s_c0[s + 1] - s_c0[s];
        const float* src = (pos < l0c)
            ? c0v + (size_t)(s_c0[s] + pos) * D
            : c1v + (size_t)(s_c1[s] + pos - l0c) * D;
        int orow = s_oo[s] + pos;
        f32x4 v = __builtin_nontemporal_load(
            reinterpret_cast<const f32x4*>(src) + lane);
        __builtin_nontemporal_store(
            v, reinterpret_cast<f32x4*>(out + (size_t)orow * D) + lane);
    }

    // ---- main loop: one token = two rows per iteration ----
    for (int tk = gwave; tk < total_tok; tk += nwaves) {
        // find sample s with item_off[s] <= tk < item_off[s+1]
        int lo = 0, hi = Bn;
        while (hi - lo > 1) {
            int mid = (lo + hi) >> 1;
            if (tk >= s_io[mid]) lo = mid; else hi = mid;
        }
        int s = lo;
        int l0c = s_c0[s + 1] - s_c0[s];
        int l1c = s_c1[s + 1] - s_c1[s];
        int orow = s_oo[s] + l0c + l1c + 2 * (tk - s_io[s]);

        // two independent 1KB loads (natural 2-deep MLP)
        f32x4 vi = __builtin_nontemporal_load(
            reinterpret_cast<const f32x4*>(item + (size_t)tk * D) + lane);
        f32x4 va = __builtin_nontemporal_load(
            reinterpret_cast<const f32x4*>(action + (size_t)tk * D) + lane);

        // contiguous 2KB store region (rows orow, orow+1)
        float* dst = out + (size_t)orow * D;
        __builtin_nontemporal_store(vi, reinterpret_cast<f32x4*>(dst) + lane);
        __builtin_nontemporal_store(va, reinterpret_cast<f32x4*>(dst + D) + lane);
    }
}

extern "C" void kernel_launch(void* const* d_in, const int* in_sizes, int n_in,
                              void* d_out, int out_size, void* d_ws, size_t ws_size,
                              hipStream_t stream) {
    const float* item   = (const float*)d_in[0];
    const float* action = (const float*)d_in[1];
    const float* c0v    = (const float*)d_in[2];
    const float* c1v    = (const float*)d_in[3];
    const int* item_len = (const int*)d_in[4];
    const int* c0_len   = (const int*)d_in[5];
    const int* c1_len   = (const int*)d_in[6];
    float* out = (float*)d_out;

    int Bn = in_sizes[4];                      // 128
    int total_rows = (out_size - Bn) / D;      // 262400
    int total_tok  = in_sizes[0] / D;          // 131072 source tokens

    // 2048 blocks x 256 threads = 8192 waves, fully resident (8 blocks/CU),
    // 16 tokens (32 rows) per wave via grid-stride.
    int grid = 2048;
    hstu_preproc_fused<<<grid, 256, 0, stream>>>(
        item, action, c0v, c1v, item_len, c0_len, c1_len,
        out, total_rows, total_tok, Bn);
}

// Round 6
// 89.967 us; speedup vs baseline: 1.0994x; 1.0994x over previous
//
#include <hip/hip_runtime.h>

#define D 256
#define MAXB 128

typedef float f32x4 __attribute__((ext_vector_type(4)));

// v2 structure (best anchor: 96.0 us), single change: loads are PLAIN (cached)
// instead of nontemporal; stores stay nontemporal. m13's 6.29 TB/s copy
// ceiling was measured with cached loads — NT loads bypass L2/L3 buffering
// for the read stream and are the last untested variable.
__global__ __launch_bounds__(256) void hstu_preproc_fused(
    const float* __restrict__ item, const float* __restrict__ action,
    const float* __restrict__ c0v, const float* __restrict__ c1v,
    const int* __restrict__ item_len, const int* __restrict__ c0_len,
    const int* __restrict__ c1_len,
    float* __restrict__ out, int total_rows, int Bn) {
    __shared__ int s_oo[MAXB + 1];
    __shared__ int s_io[MAXB + 1];
    __shared__ int s_c0[MAXB + 1];
    __shared__ int s_c1[MAXB + 1];

    int t = threadIdx.x;
    int li = 0, l0 = 0, l1 = 0;
    if (t < Bn) {
        li = item_len[t];
        l0 = c0_len[t];
        l1 = c1_len[t];
    }
    if (t == 0) { s_oo[0] = 0; s_io[0] = 0; s_c0[0] = 0; s_c1[0] = 0; }
    if (t < Bn) {
        s_oo[t + 1] = 2 * li + l0 + l1;
        s_io[t + 1] = li;
        s_c0[t + 1] = l0;
        s_c1[t + 1] = l1;
    }
    __syncthreads();
    // Hillis-Steele inclusive scan over positions 1..Bn -> exclusive offsets [0..Bn]
    for (int off = 1; off < Bn; off <<= 1) {
        int a = 0, b = 0, c = 0, d = 0;
        int idx = t + 1;
        bool act = (t < Bn) && (idx > off);
        if (act) {
            a = s_oo[idx - off];
            b = s_io[idx - off];
            c = s_c0[idx - off];
            d = s_c1[idx - off];
        }
        __syncthreads();
        if (act) {
            s_oo[idx] += a;
            s_io[idx] += b;
            s_c0[idx] += c;
            s_c1[idx] += d;
        }
        __syncthreads();
    }

    // out_len tail (second reference output), float-encoded, block 0 only
    if (blockIdx.x == 0 && t < Bn) {
        out[(size_t)total_rows * D + t] = (float)(s_oo[t + 1] - s_oo[t]);
    }

    int wave = t >> 6;
    int lane = t & 63;
    int gwave = blockIdx.x * 4 + wave;
    int nwaves = gridDim.x * 4;

    for (int r = gwave; r < total_rows; r += nwaves) {
        // wave-uniform binary search: s with out_off[s] <= r < out_off[s+1]
        int lo = 0, hi = Bn;
        while (hi - lo > 1) {
            int mid = (lo + hi) >> 1;
            if (r >= s_oo[mid]) lo = mid; else hi = mid;
        }
        int s = lo;
        int pos = r - s_oo[s];
        int l0c = s_c0[s + 1] - s_c0[s];
        int l1c = s_c1[s + 1] - s_c1[s];

        const float* src;
        if (pos < l0c) {
            src = c0v + (size_t)(s_c0[s] + pos) * D;
        } else if (pos < l0c + l1c) {
            src = c1v + (size_t)(s_c1[s] + pos - l0c) * D;
        } else {
            int q = pos - l0c - l1c;            // position within interleaved sequence
            int tk = s_io[s] + (q >> 1);        // source token row
            src = ((q & 1) ? action : item) + (size_t)tk * D;
        }

        // plain (cached) load; nontemporal store
        f32x4 v = reinterpret_cast<const f32x4*>(src)[lane];
        __builtin_nontemporal_store(
            v, reinterpret_cast<f32x4*>(out + (size_t)r * D) + lane);
    }
}

extern "C" void kernel_launch(void* const* d_in, const int* in_sizes, int n_in,
                              void* d_out, int out_size, void* d_ws, size_t ws_size,
                              hipStream_t stream) {
    const float* item   = (const float*)d_in[0];
    const float* action = (const float*)d_in[1];
    const float* c0v    = (const float*)d_in[2];
    const float* c1v    = (const float*)d_in[3];
    const int* item_len = (const int*)d_in[4];
    const int* c0_len   = (const int*)d_in[5];
    const int* c1_len   = (const int*)d_in[6];
    float* out = (float*)d_out;

    int Bn = in_sizes[4];                      // 128
    int total_rows = (out_size - Bn) / D;      // 262400

    // 2048 blocks x 256 threads = 8192 waves, fully resident (8 blocks/CU),
    // ~32 rows per wave via grid-stride.
    int grid = 2048;
    hstu_preproc_fused<<<grid, 256, 0, stream>>>(
        item, action, c0v, c1v, item_len, c0_len, c1_len, out, total_rows, Bn);
}